// Round 1
// baseline (1284.693 us; speedup 1.0000x reference)
//
#include <hip/hip_runtime.h>
#include <math.h>

// Problem constants (from reference): B=4 D=32 N=768 L=192 d_model=128 pred_len=24 in_dim=3
#define NN 768
#define DM 128
#define LL 192
#define BD 128            // B*D batches
#define OUT_OFF_A   221184
#define OUT_OFF_GEO 75718656

constexpr float TEMP_INV   = 20.0f;                    // 1/0.05
constexpr float LARGE_NEG_F = -23.025850929940457f;    // -ln(1e10)
constexpr float QK_SCALE   = 0.08838834764831845f;     // 1/sqrt(128)

// ---------------- kernel 0: min/max over cpan, csta_n ----------------
__global__ __launch_bounds__(256) void k_prep(const float* __restrict__ cpan,
                                              const float* __restrict__ csta,
                                              float* __restrict__ ws) {
  __shared__ float red[4][4];
  int t = threadIdx.x;
  float mnla = 1e30f, mxla = -1e30f, mnlo = 1e30f, mxlo = -1e30f;
  for (int i = t; i < 3072; i += 256) {
    float la = cpan[i * 2 + 0], lo = cpan[i * 2 + 1];
    mnla = fminf(mnla, la); mxla = fmaxf(mxla, la);
    mnlo = fminf(mnlo, lo); mxlo = fmaxf(mxlo, lo);
  }
  for (int off = 1; off < 64; off <<= 1) {
    mnla = fminf(mnla, __shfl_xor(mnla, off));
    mxla = fmaxf(mxla, __shfl_xor(mxla, off));
    mnlo = fminf(mnlo, __shfl_xor(mnlo, off));
    mxlo = fmaxf(mxlo, __shfl_xor(mxlo, off));
  }
  if ((t & 63) == 0) {
    int w = t >> 6;
    red[0][w] = mnla; red[1][w] = mxla; red[2][w] = mnlo; red[3][w] = mxlo;
  }
  __syncthreads();
  mnla = fminf(fminf(red[0][0], red[0][1]), fminf(red[0][2], red[0][3]));
  mxla = fmaxf(fmaxf(red[1][0], red[1][1]), fmaxf(red[1][2], red[1][3]));
  mnlo = fminf(fminf(red[2][0], red[2][1]), fminf(red[2][2], red[2][3]));
  mxlo = fmaxf(fmaxf(red[3][0], red[3][1]), fmaxf(red[3][2], red[3][3]));
  float rla = mxla - mnla + 1e-8f;
  float rlo = mxlo - mnlo + 1e-8f;
  if (t == 0) { ws[0] = mnla; ws[1] = mnlo; ws[2] = rla; ws[3] = rlo; }
  float* cn = ws + 16;
  for (int i = t; i < NN; i += 256) {
    cn[i * 2 + 0] = (csta[i * 2 + 0] - mnla) / rla;
    cn[i * 2 + 1] = (csta[i * 2 + 1] - mnlo) / rlo;
  }
}

// ---------------- kernel 1: node vectors nv1/nv2 ----------------
__global__ __launch_bounds__(64) void k_nodes(const float* __restrict__ cn,
                                              const float* __restrict__ W_sta, const float* __restrict__ b_sta,
                                              const float* __restrict__ W_n1, const float* __restrict__ b_n1,
                                              const float* __restrict__ W_n2, const float* __restrict__ b_n2,
                                              float* __restrict__ nv1, float* __restrict__ nv2) {
  __shared__ float node_c[96];
  int i = blockIdx.x, t = threadIdx.x;
  float c0 = cn[i * 2 + 0], c1 = cn[i * 2 + 1];
  if (t < 32) {
    float nv = c0 * W_sta[t * 2 + 0] + c1 * W_sta[t * 2 + 1] + b_sta[t];
    node_c[t] = sinf(nv);
    node_c[32 + t] = cosf(nv);
    node_c[64 + t] = nv;
  }
  __syncthreads();
  int half = t >> 5, o = t & 31;
  const float* W = half ? W_n2 : W_n1;
  const float* b = half ? b_n2 : b_n1;
  float acc = b[o];
  for (int j = 0; j < 96; ++j) acc = fmaf(node_c[j], W[o * 96 + j], acc);
  acc = fmaxf(acc, 0.0f);
  float ss = acc * acc;
  for (int off = 1; off < 32; off <<= 1) ss += __shfl_xor(ss, off);
  float nrm = fmaxf(sqrtf(ss), 1e-12f);
  float outv = acc / nrm;
  (half ? nv2 : nv1)[i * 32 + o] = outv;
}

// ---------------- kernel 2: geo graph ----------------
__global__ __launch_bounds__(256) void k_geo(const float* __restrict__ nv1, const float* __restrict__ nv2,
                                             const float* __restrict__ cn, const float* __restrict__ dsc_in,
                                             float* __restrict__ geo) {
  int idx = blockIdx.x * 256 + threadIdx.x;
  if (idx >= NN * NN) return;
  int i = idx / NN, j = idx % NN;
  float d1 = 0.f, d2 = 0.f;
  for (int o = 0; o < 32; ++o) {
    d1 = fmaf(nv1[i * 32 + o], nv2[j * 32 + o], d1);
    d2 = fmaf(nv1[j * 32 + o], nv2[i * 32 + o], d2);
  }
  float dla = cn[i * 2] - cn[j * 2], dlo = cn[i * 2 + 1] - cn[j * 2 + 1];
  float dist = sqrtf(dla * dla + dlo * dlo + 1e-8f);
  float x = dsc_in[0];
  float dscale = (1.0f / (1.0f + expf(-x))) * 3.0f;
  float dsim = expf(-dist * dscale);
  geo[idx] = 0.3f * (d1 + d2) + 0.4f * dsim + 0.05f;
}

// ---------------- GEMM: C[M,N] = A[M,K] @ W[N,K]^T + bias (64x64x16 tile) ----------------
__global__ __launch_bounds__(256) void k_gemm_wt(const float* __restrict__ A, const float* __restrict__ W,
                                                 const float* __restrict__ bias, float* __restrict__ C,
                                                 int K, int N) {
  __shared__ float As[16][65];
  __shared__ float Bs[16][65];
  int m0 = blockIdx.x * 64, n0 = blockIdx.y * 64;
  int t = threadIdx.x;
  int lrow = t >> 2, lk = (t & 3) << 2;
  int ty = t >> 4, tx = t & 15;
  float acc[4][4] = {};
  for (int k0 = 0; k0 < K; k0 += 16) {
    float4 av = *(const float4*)(A + (size_t)(m0 + lrow) * K + k0 + lk);
    float4 wv = *(const float4*)(W + (size_t)(n0 + lrow) * K + k0 + lk);
    __syncthreads();
    As[lk + 0][lrow] = av.x; As[lk + 1][lrow] = av.y; As[lk + 2][lrow] = av.z; As[lk + 3][lrow] = av.w;
    Bs[lk + 0][lrow] = wv.x; Bs[lk + 1][lrow] = wv.y; Bs[lk + 2][lrow] = wv.z; Bs[lk + 3][lrow] = wv.w;
    __syncthreads();
#pragma unroll
    for (int kk = 0; kk < 16; ++kk) {
      float a[4], b[4];
#pragma unroll
      for (int i = 0; i < 4; ++i) a[i] = As[kk][ty * 4 + i];
#pragma unroll
      for (int j = 0; j < 4; ++j) b[j] = Bs[kk][tx * 4 + j];
#pragma unroll
      for (int i = 0; i < 4; ++i)
#pragma unroll
        for (int j = 0; j < 4; ++j) acc[i][j] = fmaf(a[i], b[j], acc[i][j]);
    }
  }
#pragma unroll
  for (int i = 0; i < 4; ++i) {
    int r = m0 + ty * 4 + i;
#pragma unroll
    for (int j = 0; j < 4; ++j) {
      int c = n0 + tx * 4 + j;
      C[(size_t)r * N + c] = acc[i][j] + bias[c];
    }
  }
}

// ---------------- scores: S = (q k^T * scale * geo + mask)/TEMP, per batch z ----------------
__global__ __launch_bounds__(256) void k_scores(const float* __restrict__ qb, const float* __restrict__ kb,
                                                const float* __restrict__ geo, float* __restrict__ Sout) {
  int bd = blockIdx.z;
  const float* A = qb + (size_t)bd * NN * DM;
  const float* W = kb + (size_t)bd * NN * DM;
  float* C = Sout + (size_t)bd * NN * NN;
  __shared__ float As[16][65];
  __shared__ float Bs[16][65];
  int m0 = blockIdx.x * 64, n0 = blockIdx.y * 64;
  int t = threadIdx.x;
  int lrow = t >> 2, lk = (t & 3) << 2;
  int ty = t >> 4, tx = t & 15;
  float acc[4][4] = {};
  for (int k0 = 0; k0 < DM; k0 += 16) {
    float4 av = *(const float4*)(A + (size_t)(m0 + lrow) * DM + k0 + lk);
    float4 wv = *(const float4*)(W + (size_t)(n0 + lrow) * DM + k0 + lk);
    __syncthreads();
    As[lk + 0][lrow] = av.x; As[lk + 1][lrow] = av.y; As[lk + 2][lrow] = av.z; As[lk + 3][lrow] = av.w;
    Bs[lk + 0][lrow] = wv.x; Bs[lk + 1][lrow] = wv.y; Bs[lk + 2][lrow] = wv.z; Bs[lk + 3][lrow] = wv.w;
    __syncthreads();
#pragma unroll
    for (int kk = 0; kk < 16; ++kk) {
      float a[4], b[4];
#pragma unroll
      for (int i = 0; i < 4; ++i) a[i] = As[kk][ty * 4 + i];
#pragma unroll
      for (int j = 0; j < 4; ++j) b[j] = Bs[kk][tx * 4 + j];
#pragma unroll
      for (int i = 0; i < 4; ++i)
#pragma unroll
        for (int j = 0; j < 4; ++j) acc[i][j] = fmaf(a[i], b[j], acc[i][j]);
    }
  }
#pragma unroll
  for (int i = 0; i < 4; ++i) {
    int r = m0 + ty * 4 + i;
#pragma unroll
    for (int j = 0; j < 4; ++j) {
      int c = n0 + tx * 4 + j;
      float g = geo[(size_t)r * NN + c];
      float s = acc[i][j] * QK_SCALE * g;
      if (g == 0.0f) s += LARGE_NEG_F;
      C[(size_t)r * NN + c] = s * TEMP_INV;
    }
  }
}

// ---------------- softmax in place over rows of 768 ----------------
__global__ __launch_bounds__(256) void k_softmax(float* __restrict__ S) {
  size_t row = blockIdx.x;
  float* p = S + row * NN;
  int t = threadIdx.x;
  float v0 = p[t], v1 = p[t + 256], v2 = p[t + 512];
  float m = fmaxf(fmaxf(v0, v1), v2);
  for (int off = 1; off < 64; off <<= 1) m = fmaxf(m, __shfl_xor(m, off));
  __shared__ float rm[4];
  __shared__ float rs[4];
  if ((t & 63) == 0) rm[t >> 6] = m;
  __syncthreads();
  m = fmaxf(fmaxf(rm[0], rm[1]), fmaxf(rm[2], rm[3]));
  float e0 = expf(v0 - m), e1 = expf(v1 - m), e2 = expf(v2 - m);
  float s = e0 + e1 + e2;
  for (int off = 1; off < 64; off <<= 1) s += __shfl_xor(s, off);
  if ((t & 63) == 0) rs[t >> 6] = s;
  __syncthreads();
  s = rs[0] + rs[1] + rs[2] + rs[3];
  float inv = 1.0f / s;
  p[t] = e0 * inv; p[t + 256] = e1 * inv; p[t + 512] = e2 * inv;
}

// ---------------- t = A @ v per batch (A: 768x768 from d_out, B: 768x128) ----------------
__global__ __launch_bounds__(256) void k_gemm_nn(const float* __restrict__ Abase, const float* __restrict__ Bbase,
                                                 float* __restrict__ Cbase) {
  int bd = blockIdx.z;
  const float* A = Abase + (size_t)bd * NN * NN;
  const float* B = Bbase + (size_t)bd * NN * DM;
  float* C = Cbase + (size_t)bd * NN * DM;
  __shared__ float As[16][65];
  __shared__ float Bs[16][65];
  int m0 = blockIdx.x * 64, n0 = blockIdx.y * 64;
  int t = threadIdx.x;
  int lrow = t >> 2, lk = (t & 3) << 2;
  int bk = t >> 4, bn = (t & 15) << 2;
  int ty = t >> 4, tx = t & 15;
  float acc[4][4] = {};
  for (int k0 = 0; k0 < NN; k0 += 16) {
    float4 av = *(const float4*)(A + (size_t)(m0 + lrow) * NN + k0 + lk);
    float4 bv = *(const float4*)(B + (size_t)(k0 + bk) * DM + n0 + bn);
    __syncthreads();
    As[lk + 0][lrow] = av.x; As[lk + 1][lrow] = av.y; As[lk + 2][lrow] = av.z; As[lk + 3][lrow] = av.w;
    Bs[bk][bn + 0] = bv.x; Bs[bk][bn + 1] = bv.y; Bs[bk][bn + 2] = bv.z; Bs[bk][bn + 3] = bv.w;
    __syncthreads();
#pragma unroll
    for (int kk = 0; kk < 16; ++kk) {
      float a[4], b[4];
#pragma unroll
      for (int i = 0; i < 4; ++i) a[i] = As[kk][ty * 4 + i];
#pragma unroll
      for (int j = 0; j < 4; ++j) b[j] = Bs[kk][tx * 4 + j];
#pragma unroll
      for (int i = 0; i < 4; ++i)
#pragma unroll
        for (int j = 0; j < 4; ++j) acc[i][j] = fmaf(a[i], b[j], acc[i][j]);
    }
  }
#pragma unroll
  for (int i = 0; i < 4; ++i) {
    int r = m0 + ty * 4 + i;
#pragma unroll
    for (int j = 0; j < 4; ++j) {
      int c = n0 + tx * 4 + j;
      C[(size_t)r * DM + c] = acc[i][j];
    }
  }
}

// ---------------- final: out[b,c,n,p] = b_fc2[c] + sum_d W_fc2[c,d]*(b_fc1[p] + t[b*32+d,n,:]·W_fc1[p,:]) ----
__global__ __launch_bounds__(256) void k_final(const float* __restrict__ tmat, const float* __restrict__ W_fc1,
                                               const float* __restrict__ b_fc1, const float* __restrict__ W_fc2,
                                               const float* __restrict__ b_fc2, float* __restrict__ out) {
  int b = blockIdx.x / NN, n = blockIdx.x % NN;
  __shared__ float tl[32 * 128];
  __shared__ float w1[24 * 128];
  __shared__ float o1[32 * 24];
  int t = threadIdx.x;
  for (int idx = t; idx < 4096; idx += 256) {
    int d = idx >> 7, j = idx & 127;
    tl[idx] = tmat[((size_t)(b * 32 + d) * NN + n) * DM + j];
  }
  for (int idx = t; idx < 3072; idx += 256) w1[idx] = W_fc1[idx];
  __syncthreads();
  for (int task = t; task < 768; task += 256) {
    int d = task / 24, pp = task % 24;
    float acc = b_fc1[pp];
#pragma unroll 8
    for (int j = 0; j < 128; ++j) acc = fmaf(tl[d * 128 + j], w1[pp * 128 + j], acc);
    o1[task] = acc;
  }
  __syncthreads();
  if (t < 72) {
    int c = t / 24, pp = t % 24;
    float acc = b_fc2[c];
#pragma unroll
    for (int d = 0; d < 32; ++d) acc = fmaf(W_fc2[c * 32 + d], o1[d * 24 + pp], acc);
    out[(((size_t)b * 3 + c) * NN + n) * 24 + pp] = acc;
  }
}

extern "C" void kernel_launch(void* const* d_in, const int* in_sizes, int n_in,
                              void* d_out, int out_size, void* d_ws, size_t ws_size,
                              hipStream_t stream) {
  const float* x     = (const float*)d_in[1];
  const float* csta  = (const float*)d_in[2];
  const float* cpan  = (const float*)d_in[3];
  const float* Wq    = (const float*)d_in[4];
  const float* bq    = (const float*)d_in[5];
  const float* Wk    = (const float*)d_in[6];
  const float* bk    = (const float*)d_in[7];
  const float* Wv    = (const float*)d_in[8];
  const float* bv    = (const float*)d_in[9];
  const float* W_sta = (const float*)d_in[10];
  const float* b_sta = (const float*)d_in[11];
  const float* W_n1  = (const float*)d_in[12];
  const float* b_n1  = (const float*)d_in[13];
  const float* W_n2  = (const float*)d_in[14];
  const float* b_n2  = (const float*)d_in[15];
  const float* dsc   = (const float*)d_in[16];
  const float* W_fc1 = (const float*)d_in[17];
  const float* b_fc1 = (const float*)d_in[18];
  const float* W_fc2 = (const float*)d_in[19];
  const float* b_fc2 = (const float*)d_in[20];

  float* out  = (float*)d_out;
  float* Aout = out + OUT_OFF_A;
  float* geo  = out + OUT_OFF_GEO;

  float* ws   = (float*)d_ws;
  float* cn   = ws + 16;
  float* nv1  = ws + 2048;
  float* nv2  = ws + 2048 + 24576;
  float* q    = ws + 51200;
  float* kbuf = q + (size_t)BD * NN * DM;
  float* v    = kbuf + (size_t)BD * NN * DM;
  float* tmat = q;  // q dead after k_scores; reuse for t

  k_prep<<<1, 256, 0, stream>>>(cpan, csta, ws);
  k_nodes<<<768, 64, 0, stream>>>(cn, W_sta, b_sta, W_n1, b_n1, W_n2, b_n2, nv1, nv2);
  k_geo<<<(NN * NN + 255) / 256, 256, 0, stream>>>(nv1, nv2, cn, dsc, geo);

  dim3 gq(BD * NN / 64, DM / 64, 1);
  k_gemm_wt<<<gq, 256, 0, stream>>>(x, Wq, bq, q, LL, DM);
  k_gemm_wt<<<gq, 256, 0, stream>>>(x, Wk, bk, kbuf, LL, DM);
  k_gemm_wt<<<gq, 256, 0, stream>>>(x, Wv, bv, v, LL, DM);

  dim3 gs(NN / 64, NN / 64, BD);
  k_scores<<<gs, 256, 0, stream>>>(q, kbuf, geo, Aout);
  k_softmax<<<BD * NN, 256, 0, stream>>>(Aout);

  dim3 ga(NN / 64, DM / 64, BD);
  k_gemm_nn<<<ga, 256, 0, stream>>>(Aout, v, tmat);

  k_final<<<4 * NN, 256, 0, stream>>>(tmat, W_fc1, b_fc1, W_fc2, b_fc2, out);
}

// Round 3
// 555.321 us; speedup vs baseline: 2.3134x; 2.3134x over previous
//
#include <hip/hip_runtime.h>
#include <math.h>

// B=4 D=32 N=768 L=192 d_model=128 pred_len=24 in_dim=3
#define NN 768
#define DM 128
#define LL 192
#define BD 128
#define OUT_OFF_A   221184
#define OUT_OFF_GEO 75718656

// ws layout (f32 element offsets) — sizes verified this time:
//  qh : bf16 [98304][128] = 6,291,456 f32 slots
//  kh : bf16 [98304][128] = 6,291,456
//  vT : bf16 [128][128][768] = 6,291,456
//  xh : bf16 [98304][192] = 9,437,184
//  tmat: f32 [98304][128] = 12,582,912  (aliases qh+kh, dead after k_scores)
#define WS_CN   16
#define WS_NV1  2048
#define WS_NV2  26624
#define WS_PART 51200            // [128][768][6] f32  -> [51200, 641024)
#define WS_INV  641024           // [98304] f32        -> [641024, 739328)
#define WS_QH   739328           // -> [739328, 7030784)
#define WS_KH   7030784          // -> [7030784, 13322240)
#define WS_VT   13322240         // -> [13322240, 19613696)
#define WS_XH   19613696         // -> [19613696, 29050880)   peak 116.2 MB
#define WS_T    739328           // aliases qh+kh: [739328, 13322240)

constexpr float TEMP_INV    = 20.0f;                  // 1/0.05
constexpr float LARGE_NEG_F = -23.025850929940457f;   // -ln(1e10)
constexpr float QK_SCALE    = 0.08838834764831845f;   // 1/sqrt(128)

typedef unsigned short u16;
typedef u16 u16x8 __attribute__((ext_vector_type(8)));
typedef u16 u16x4 __attribute__((ext_vector_type(4)));
typedef __bf16 bf16x8 __attribute__((ext_vector_type(8)));
typedef float f32x4 __attribute__((ext_vector_type(4)));

__device__ __forceinline__ u16 f2b(float f) {   // f32 -> bf16 RNE
  unsigned u = __builtin_bit_cast(unsigned, f);
  return (u16)((u + 0x7fffu + ((u >> 16) & 1u)) >> 16);
}

// ---------------- kernel 0: min/max over cpan, csta_n ----------------
__global__ __launch_bounds__(256) void k_prep(const float* __restrict__ cpan,
                                              const float* __restrict__ csta,
                                              float* __restrict__ ws) {
  __shared__ float red[4][4];
  int t = threadIdx.x;
  float mnla = 1e30f, mxla = -1e30f, mnlo = 1e30f, mxlo = -1e30f;
  for (int i = t; i < 3072; i += 256) {
    float la = cpan[i * 2 + 0], lo = cpan[i * 2 + 1];
    mnla = fminf(mnla, la); mxla = fmaxf(mxla, la);
    mnlo = fminf(mnlo, lo); mxlo = fmaxf(mxlo, lo);
  }
  for (int off = 1; off < 64; off <<= 1) {
    mnla = fminf(mnla, __shfl_xor(mnla, off));
    mxla = fmaxf(mxla, __shfl_xor(mxla, off));
    mnlo = fminf(mnlo, __shfl_xor(mnlo, off));
    mxlo = fmaxf(mxlo, __shfl_xor(mxlo, off));
  }
  if ((t & 63) == 0) {
    int w = t >> 6;
    red[0][w] = mnla; red[1][w] = mxla; red[2][w] = mnlo; red[3][w] = mxlo;
  }
  __syncthreads();
  mnla = fminf(fminf(red[0][0], red[0][1]), fminf(red[0][2], red[0][3]));
  mxla = fmaxf(fmaxf(red[1][0], red[1][1]), fmaxf(red[1][2], red[1][3]));
  mnlo = fminf(fminf(red[2][0], red[2][1]), fminf(red[2][2], red[2][3]));
  mxlo = fmaxf(fmaxf(red[3][0], red[3][1]), fmaxf(red[3][2], red[3][3]));
  float rla = mxla - mnla + 1e-8f;
  float rlo = mxlo - mnlo + 1e-8f;
  float* cn = ws + WS_CN;
  for (int i = t; i < NN; i += 256) {
    cn[i * 2 + 0] = (csta[i * 2 + 0] - mnla) / rla;
    cn[i * 2 + 1] = (csta[i * 2 + 1] - mnlo) / rlo;
  }
}

// ---------------- kernel 1: node vectors nv1/nv2 ----------------
__global__ __launch_bounds__(64) void k_nodes(const float* __restrict__ cn,
                                              const float* __restrict__ W_sta, const float* __restrict__ b_sta,
                                              const float* __restrict__ W_n1, const float* __restrict__ b_n1,
                                              const float* __restrict__ W_n2, const float* __restrict__ b_n2,
                                              float* __restrict__ nv1, float* __restrict__ nv2) {
  __shared__ float node_c[96];
  int i = blockIdx.x, t = threadIdx.x;
  float c0 = cn[i * 2 + 0], c1 = cn[i * 2 + 1];
  if (t < 32) {
    float nv = c0 * W_sta[t * 2 + 0] + c1 * W_sta[t * 2 + 1] + b_sta[t];
    node_c[t] = sinf(nv);
    node_c[32 + t] = cosf(nv);
    node_c[64 + t] = nv;
  }
  __syncthreads();
  int half = t >> 5, o = t & 31;
  const float* W = half ? W_n2 : W_n1;
  const float* b = half ? b_n2 : b_n1;
  float acc = b[o];
  for (int j = 0; j < 96; ++j) acc = fmaf(node_c[j], W[o * 96 + j], acc);
  acc = fmaxf(acc, 0.0f);
  float ss = acc * acc;
  for (int off = 1; off < 32; off <<= 1) ss += __shfl_xor(ss, off);
  float nrm = fmaxf(sqrtf(ss), 1e-12f);
  (half ? nv2 : nv1)[i * 32 + o] = acc / nrm;
}

// ---------------- kernel 2: geo graph ----------------
__global__ __launch_bounds__(256) void k_geo(const float* __restrict__ nv1, const float* __restrict__ nv2,
                                             const float* __restrict__ cn, const float* __restrict__ dsc_in,
                                             float* __restrict__ geo) {
  int idx = blockIdx.x * 256 + threadIdx.x;
  if (idx >= NN * NN) return;
  int i = idx / NN, j = idx % NN;
  float d1 = 0.f, d2 = 0.f;
  for (int o = 0; o < 32; ++o) {
    d1 = fmaf(nv1[i * 32 + o], nv2[j * 32 + o], d1);
    d2 = fmaf(nv1[j * 32 + o], nv2[i * 32 + o], d2);
  }
  float dla = cn[i * 2] - cn[j * 2], dlo = cn[i * 2 + 1] - cn[j * 2 + 1];
  float dist = sqrtf(dla * dla + dlo * dlo + 1e-8f);
  float x = dsc_in[0];
  float dscale = (1.0f / (1.0f + expf(-x))) * 3.0f;
  float dsim = expf(-dist * dscale);
  geo[idx] = 0.3f * (d1 + d2) + 0.4f * dsim + 0.05f;
}

// ---------------- x -> bf16 ----------------
__global__ __launch_bounds__(256) void k_cvt(const float* __restrict__ x, u16* __restrict__ xh) {
  size_t i = ((size_t)blockIdx.x * 256 + threadIdx.x) * 4;
  float4 v = *(const float4*)(x + i);
  u16x4 o = {f2b(v.x), f2b(v.y), f2b(v.z), f2b(v.w)};
  *(u16x4*)(xh + i) = o;
}

// ---------------- QKV projection: bf16 MFMA, tile 128x128, K=192 ----------------
// z=0: q row-major bf16 [98304][128]; z=1: k same; z=2: vT [bd][128 col][768 row]
__global__ __launch_bounds__(256) void k_qkv(const u16* __restrict__ xh,
      const float* __restrict__ Wq, const float* __restrict__ bq,
      const float* __restrict__ Wk, const float* __restrict__ bk,
      const float* __restrict__ Wv, const float* __restrict__ bv,
      u16* __restrict__ qo, u16* __restrict__ ko, u16* __restrict__ vTo) {
  int z = blockIdx.y;
  const float* W    = (z == 0) ? Wq : ((z == 1) ? Wk : Wv);
  const float* bias = (z == 0) ? bq : ((z == 1) ? bk : bv);
  __shared__ u16 xs[128 * 192];
  __shared__ u16 wsd[128 * 192];
  int m0 = blockIdx.x * 128;
  int t = threadIdx.x;
  for (int i = t; i < 3072; i += 256) {       // 16B chunks: 128 rows x 24
    int row = i / 24, c = i % 24;
    u16x8 v8 = *(const u16x8*)(xh + (size_t)(m0 + row) * 192 + c * 8);
    int byte = (row * 384 + c * 16) ^ ((row & 7) << 4);
    *(u16x8*)((char*)xs + byte) = v8;
    const float* src = W + row * 192 + c * 8;
    u16x8 w8;
#pragma unroll
    for (int j = 0; j < 8; ++j) w8[j] = f2b(src[j]);
    *(u16x8*)((char*)wsd + byte) = w8;
  }
  __syncthreads();
  int w = t >> 6, l = t & 63, wr = w >> 1, wc = w & 1, lg = l >> 4, lm = l & 15;
  f32x4 acc[4][4] = {};
#pragma unroll
  for (int kk = 0; kk < 6; ++kk) {
    bf16x8 a[4], b[4];
#pragma unroll
    for (int fr = 0; fr < 4; ++fr) {
      int row = wr * 64 + fr * 16 + lm;
      int byte = (row * 384 + kk * 64 + lg * 16) ^ ((row & 7) << 4);
      a[fr] = __builtin_bit_cast(bf16x8, *(const u16x8*)((const char*)xs + byte));
    }
#pragma unroll
    for (int fc = 0; fc < 4; ++fc) {
      int row = wc * 64 + fc * 16 + lm;
      int byte = (row * 384 + kk * 64 + lg * 16) ^ ((row & 7) << 4);
      b[fc] = __builtin_bit_cast(bf16x8, *(const u16x8*)((const char*)wsd + byte));
    }
#pragma unroll
    for (int fr = 0; fr < 4; ++fr)
#pragma unroll
      for (int fc = 0; fc < 4; ++fc)
        acc[fr][fc] = __builtin_amdgcn_mfma_f32_16x16x32_bf16(a[fr], b[fc], acc[fr][fc], 0, 0, 0);
  }
  if (z < 2) {
    u16* out = (z == 0) ? qo : ko;
#pragma unroll
    for (int fr = 0; fr < 4; ++fr)
#pragma unroll
      for (int fc = 0; fc < 4; ++fc) {
        int col = wc * 64 + fc * 16 + lm;
        float bb = bias[col];
#pragma unroll
        for (int r = 0; r < 4; ++r) {
          int row = m0 + wr * 64 + fr * 16 + lg * 4 + r;
          out[(size_t)row * 128 + col] = f2b(acc[fr][fc][r] + bb);
        }
      }
  } else {
    u16* es = xs;   // reuse: 128*132 = 16896 u16
    __syncthreads();
#pragma unroll
    for (int fr = 0; fr < 4; ++fr)
#pragma unroll
      for (int fc = 0; fc < 4; ++fc) {
        int col = wc * 64 + fc * 16 + lm;
        float bb = bias[col];
#pragma unroll
        for (int r = 0; r < 4; ++r) {
          int row = wr * 64 + fr * 16 + lg * 4 + r;
          es[row * 132 + col] = f2b(acc[fr][fc][r] + bb);
        }
      }
    __syncthreads();
    int col = t >> 1, half = t & 1;
    int bd = m0 / NN, ml = m0 % NN;
    u16* dst = vTo + (size_t)bd * 98304 + (size_t)col * NN + ml + half * 64;
#pragma unroll
    for (int i = 0; i < 64; i += 8) {
      u16x8 v8;
#pragma unroll
      for (int j = 0; j < 8; ++j) v8[j] = es[(half * 64 + i + j) * 132 + col];
      *(u16x8*)(dst + i) = v8;
    }
  }
}

// ---------------- scores: u = exp((q k^T scale * geo + mask)/TEMP), + row partial sums ----
__global__ __launch_bounds__(256) void k_scores(const u16* __restrict__ qh, const u16* __restrict__ kh,
                                                const float* __restrict__ geo, float* __restrict__ Aout,
                                                float* __restrict__ partial) {
  int bd = blockIdx.z;
  int m0 = blockIdx.x * 128, n0 = blockIdx.y * 128;
  __shared__ u16 qs[128 * 128];
  __shared__ u16 ks[128 * 128];
  __shared__ float rsum[2][64][2];
  int t = threadIdx.x;
  const u16* qg = qh + (size_t)bd * 98304 + (size_t)m0 * 128;
  const u16* kg = kh + (size_t)bd * 98304 + (size_t)n0 * 128;
  for (int i = t; i < 2048; i += 256) {   // 16B chunks: 128 rows x 16
    int row = i >> 4, c = i & 15;
    u16x8 a8 = *(const u16x8*)(qg + row * 128 + c * 8);
    u16x8 b8 = *(const u16x8*)(kg + row * 128 + c * 8);
    int byte = (row * 256 + c * 16) ^ ((row & 7) << 4);
    *(u16x8*)((char*)qs + byte) = a8;
    *(u16x8*)((char*)ks + byte) = b8;
  }
  __syncthreads();
  int w = t >> 6, l = t & 63, wr = w >> 1, wc = w & 1, lg = l >> 4, lm = l & 15;
  f32x4 acc[4][4] = {};
#pragma unroll
  for (int kk = 0; kk < 4; ++kk) {
    bf16x8 a[4], b[4];
#pragma unroll
    for (int fr = 0; fr < 4; ++fr) {
      int row = wr * 64 + fr * 16 + lm;
      int byte = (row * 256 + kk * 64 + lg * 16) ^ ((row & 7) << 4);
      a[fr] = __builtin_bit_cast(bf16x8, *(const u16x8*)((const char*)qs + byte));
    }
#pragma unroll
    for (int fc = 0; fc < 4; ++fc) {
      int row = wc * 64 + fc * 16 + lm;
      int byte = (row * 256 + kk * 64 + lg * 16) ^ ((row & 7) << 4);
      b[fc] = __builtin_bit_cast(bf16x8, *(const u16x8*)((const char*)ks + byte));
    }
#pragma unroll
    for (int fr = 0; fr < 4; ++fr)
#pragma unroll
      for (int fc = 0; fc < 4; ++fc)
        acc[fr][fc] = __builtin_amdgcn_mfma_f32_16x16x32_bf16(a[fr], b[fc], acc[fr][fc], 0, 0, 0);
  }
  float psum[4][4] = {};   // [fr][r]
  float* Ab = Aout + (size_t)bd * 589824;
#pragma unroll
  for (int fr = 0; fr < 4; ++fr)
#pragma unroll
    for (int fc = 0; fc < 4; ++fc) {
      int row = m0 + wr * 64 + fr * 16 + lg * 4;
      int col = n0 + wc * 64 + fc * 16 + lm;
#pragma unroll
      for (int r = 0; r < 4; ++r) {
        float g = geo[(size_t)(row + r) * NN + col];
        float lgt = (acc[fr][fc][r] * QK_SCALE * g + (g == 0.0f ? LARGE_NEG_F : 0.0f)) * TEMP_INV;
        float u = __expf(fminf(lgt, 85.0f));
        Ab[(size_t)(row + r) * NN + col] = u;
        psum[fr][r] += u;
      }
    }
#pragma unroll
  for (int off = 1; off < 16; off <<= 1)
#pragma unroll
    for (int fr = 0; fr < 4; ++fr)
#pragma unroll
      for (int r = 0; r < 4; ++r) psum[fr][r] += __shfl_xor(psum[fr][r], off);
  if (lm == 0) {
#pragma unroll
    for (int fr = 0; fr < 4; ++fr)
#pragma unroll
      for (int r = 0; r < 4; ++r) rsum[wr][fr * 16 + lg * 4 + r][wc] = psum[fr][r];
  }
  __syncthreads();
  if (t < 128) {
    float s = rsum[t >> 6][t & 63][0] + rsum[t >> 6][t & 63][1];
    partial[((size_t)bd * NN + m0 + t) * 6 + blockIdx.y] = s;
  }
}

// ---------------- reduce partials -> 1/rowsum ----------------
__global__ __launch_bounds__(256) void k_rowsum(const float* __restrict__ partial, float* __restrict__ invs) {
  int i = blockIdx.x * 256 + threadIdx.x;   // 98304 rows
  const float* p = partial + (size_t)i * 6;
  invs[i] = 1.0f / (p[0] + p[1] + p[2] + p[3] + p[4] + p[5]);
}

// ---------------- PV: normalize u->p in place (writes final A) and t = p @ v ----------------
__global__ __launch_bounds__(256) void k_pv(float* __restrict__ Aout, const float* __restrict__ invs,
                                            const u16* __restrict__ vT, float* __restrict__ tmat) {
  int bd = blockIdx.y;
  int m0 = blockIdx.x * 128;
  __shared__ u16 ps[128 * 64];
  __shared__ u16 vs[128 * 64];
  __shared__ float invl[128];
  int t = threadIdx.x;
  float* Ab = Aout + (size_t)bd * 589824;
  const u16* vb = vT + (size_t)bd * 98304;
  if (t < 128) invl[t] = invs[(size_t)bd * NN + m0 + t];
  int w = t >> 6, l = t & 63, wr = w >> 1, wc = w & 1, lg = l >> 4, lm = l & 15;
  f32x4 acc[4][4] = {};
  for (int k0 = 0; k0 < NN; k0 += 64) {
    __syncthreads();
    for (int i = t; i < 2048; i += 256) {   // p: 128 rows x 16 float4
      int row = i >> 4, c = i & 15;
      float* ap = Ab + (size_t)(m0 + row) * NN + k0 + c * 4;
      float4 u4 = *(float4*)ap;
      float inv = invl[row];
      u4.x *= inv; u4.y *= inv; u4.z *= inv; u4.w *= inv;
      *(float4*)ap = u4;
      u16x4 p4 = {f2b(u4.x), f2b(u4.y), f2b(u4.z), f2b(u4.w)};
      int byte = (row * 128 + c * 8) ^ ((row & 7) << 4);
      *(u16x4*)((char*)ps + byte) = p4;
    }
    for (int i = t; i < 1024; i += 256) {   // vT: 128 cols x 8 chunks of 8
      int row = i >> 3, c = i & 7;
      u16x8 v8 = *(const u16x8*)(vb + (size_t)row * NN + k0 + c * 8);
      int byte = (row * 128 + c * 16) ^ ((row & 7) << 4);
      *(u16x8*)((char*)vs + byte) = v8;
    }
    __syncthreads();
#pragma unroll
    for (int kk = 0; kk < 2; ++kk) {
      bf16x8 a[4], b[4];
#pragma unroll
      for (int fr = 0; fr < 4; ++fr) {
        int row = wr * 64 + fr * 16 + lm;
        int byte = (row * 128 + kk * 64 + lg * 16) ^ ((row & 7) << 4);
        a[fr] = __builtin_bit_cast(bf16x8, *(const u16x8*)((const char*)ps + byte));
      }
#pragma unroll
      for (int fc = 0; fc < 4; ++fc) {
        int row = wc * 64 + fc * 16 + lm;
        int byte = (row * 128 + kk * 64 + lg * 16) ^ ((row & 7) << 4);
        b[fc] = __builtin_bit_cast(bf16x8, *(const u16x8*)((const char*)vs + byte));
      }
#pragma unroll
      for (int fr = 0; fr < 4; ++fr)
#pragma unroll
        for (int fc = 0; fc < 4; ++fc)
          acc[fr][fc] = __builtin_amdgcn_mfma_f32_16x16x32_bf16(a[fr], b[fc], acc[fr][fc], 0, 0, 0);
    }
  }
#pragma unroll
  for (int fr = 0; fr < 4; ++fr)
#pragma unroll
    for (int fc = 0; fc < 4; ++fc) {
      int col = wc * 64 + fc * 16 + lm;
#pragma unroll
      for (int r = 0; r < 4; ++r) {
        int row = m0 + wr * 64 + fr * 16 + lg * 4 + r;
        tmat[((size_t)bd * NN + row) * 128 + col] = acc[fr][fc][r];
      }
    }
}

// ---------------- final: fc1 + reshape + fc2 ----------------
__global__ __launch_bounds__(256) void k_final(const float* __restrict__ tmat, const float* __restrict__ W_fc1,
                                               const float* __restrict__ b_fc1, const float* __restrict__ W_fc2,
                                               const float* __restrict__ b_fc2, float* __restrict__ out) {
  int b = blockIdx.x / NN, n = blockIdx.x % NN;
  __shared__ float tl[32 * 128];
  __shared__ float w1[24 * 128];
  __shared__ float o1[32 * 24];
  int t = threadIdx.x;
  for (int idx = t; idx < 4096; idx += 256) {
    int d = idx >> 7, j = idx & 127;
    tl[idx] = tmat[((size_t)(b * 32 + d) * NN + n) * DM + j];
  }
  for (int idx = t; idx < 3072; idx += 256) w1[idx] = W_fc1[idx];
  __syncthreads();
  for (int task = t; task < 768; task += 256) {
    int d = task / 24, pp = task % 24;
    float acc = b_fc1[pp];
#pragma unroll 8
    for (int j = 0; j < 128; ++j) acc = fmaf(tl[d * 128 + j], w1[pp * 128 + j], acc);
    o1[task] = acc;
  }
  __syncthreads();
  if (t < 72) {
    int c = t / 24, pp = t % 24;
    float acc = b_fc2[c];
#pragma unroll
    for (int d = 0; d < 32; ++d) acc = fmaf(W_fc2[c * 32 + d], o1[d * 24 + pp], acc);
    out[(((size_t)b * 3 + c) * NN + n) * 24 + pp] = acc;
  }
}

extern "C" void kernel_launch(void* const* d_in, const int* in_sizes, int n_in,
                              void* d_out, int out_size, void* d_ws, size_t ws_size,
                              hipStream_t stream) {
  (void)in_sizes; (void)n_in; (void)out_size; (void)ws_size;
  const float* x     = (const float*)d_in[1];
  const float* csta  = (const float*)d_in[2];
  const float* cpan  = (const float*)d_in[3];
  const float* Wq    = (const float*)d_in[4];
  const float* bq    = (const float*)d_in[5];
  const float* Wk    = (const float*)d_in[6];
  const float* bk    = (const float*)d_in[7];
  const float* Wv    = (const float*)d_in[8];
  const float* bv    = (const float*)d_in[9];
  const float* W_sta = (const float*)d_in[10];
  const float* b_sta = (const float*)d_in[11];
  const float* W_n1  = (const float*)d_in[12];
  const float* b_n1  = (const float*)d_in[13];
  const float* W_n2  = (const float*)d_in[14];
  const float* b_n2  = (const float*)d_in[15];
  const float* dsc   = (const float*)d_in[16];
  const float* W_fc1 = (const float*)d_in[17];
  const float* b_fc1 = (const float*)d_in[18];
  const float* W_fc2 = (const float*)d_in[19];
  const float* b_fc2 = (const float*)d_in[20];

  float* out  = (float*)d_out;
  float* Aout = out + OUT_OFF_A;
  float* geo  = out + OUT_OFF_GEO;

  float* ws   = (float*)d_ws;
  float* cn   = ws + WS_CN;
  float* nv1  = ws + WS_NV1;
  float* nv2  = ws + WS_NV2;
  float* part = ws + WS_PART;
  float* invs = ws + WS_INV;
  u16*   qh   = (u16*)(ws + WS_QH);
  u16*   kh   = (u16*)(ws + WS_KH);
  u16*   vT   = (u16*)(ws + WS_VT);
  u16*   xh   = (u16*)(ws + WS_XH);
  float* tmat = ws + WS_T;   // aliases qh+kh (dead after k_scores)

  k_prep<<<1, 256, 0, stream>>>(cpan, csta, ws);
  k_nodes<<<768, 64, 0, stream>>>(cn, W_sta, b_sta, W_n1, b_n1, W_n2, b_n2, nv1, nv2);
  k_geo<<<(NN * NN + 255) / 256, 256, 0, stream>>>(nv1, nv2, cn, dsc, geo);

  k_cvt<<<18432, 256, 0, stream>>>(x, xh);
  k_qkv<<<dim3(768, 3), 256, 0, stream>>>(xh, Wq, bq, Wk, bk, Wv, bv, qh, kh, vT);

  k_scores<<<dim3(6, 6, BD), 256, 0, stream>>>(qh, kh, geo, Aout, part);
  k_rowsum<<<384, 256, 0, stream>>>(part, invs);
  k_pv<<<dim3(6, BD), 256, 0, stream>>>(Aout, invs, vT, tmat);

  k_final<<<4 * NN, 256, 0, stream>>>(tmat, W_fc1, b_fc1, W_fc2, b_fc2, out);
}